// Round 9
// baseline (548.176 us; speedup 1.0000x reference)
//
#include <hip/hip_runtime.h>
#include <math.h>

#define NN 25000
#define NE 400000
#define HH 128
#define NH (NN*HH)
#define NBINS 256

// gaussian smearing: offset_k = k*8/15, coeff = -0.5/(8/15)^2 = -1.7578125
#define GS_STEP  (8.0f/15.0f)
#define GS_COEFF (-1.7578125f)
#define LOG2E    1.442695041f
#define LN2      0.6931471806f
#define BINSC    ((float)NBINS / 8.0f)

typedef float f32x2 __attribute__((ext_vector_type(2)));

// ---------------- node embedding: h = x @ node_w + node_b ----------------
__global__ __launch_bounds__(256) void k_node_embed(
    const float* __restrict__ x, const float* __restrict__ w,
    const float* __restrict__ b, float* __restrict__ h) {
  int t = blockIdx.x * 256 + threadIdx.x;
  if (t >= NH) return;
  int n = t >> 7, j = t & 127;
  const float* xr = x + n * 6;
  float acc = b[j];
#pragma unroll
  for (int k = 0; k < 6; ++k) acc = fmaf(xr[k], w[k * HH + j], acc);
  h[t] = acc;
}

// ---------------- fused prep: weight repack + gaussian LUT, both layers ----
// grid: x in [0,385), y = layer. Blocks x<256: pack Wp/biasv. x>=256: LUT bins.
__global__ __launch_bounds__(256) void k_prep(
    const float* __restrict__ f1w, const float* __restrict__ s1w,
    const float* __restrict__ f1b, const float* __restrict__ s1b,
    const float* __restrict__ f2w, const float* __restrict__ s2w,
    const float* __restrict__ f2b, const float* __restrict__ s2b,
    float* __restrict__ Wp1, float* __restrict__ bv1, float* __restrict__ L1,
    float* __restrict__ Wp2, float* __restrict__ bv2, float* __restrict__ L2) {
  const int layer = blockIdx.y;
  const float* fw = layer ? f2w : f1w;
  const float* sw = layer ? s2w : s1w;
  const float* fb = layer ? f2b : f1b;
  const float* sb = layer ? s2b : s1b;
  float* Wp = layer ? Wp2 : Wp1;
  float* biasv = layer ? bv2 : bv1;
  float* LUT = layer ? L2 : L1;
  const int bx = blockIdx.x;
  const int tid = threadIdx.x;
  if (bx < 256) {
    const int t = bx * 256 + tid;
    if (t < 512) biasv[t] = (t < 256) ? ((t & 1) ? sb[t >> 1] : fb[t >> 1]) : 0.f;
    const int k = t >> 9, c = t & 511;
    const int cc = c & 255;
    const int row = ((c >= 256) ? 128 : 0) + k;
    const float* m = (cc & 1) ? sw : fw;
    Wp[t] = m[row * HH + (cc >> 1)];
  } else {
    const int bin = (bx - 256) * 2 + (tid >> 7);
    if (bin > NBINS) return;
    const int j = tid & 127;
    const float* fw3 = fw + 256 * HH;
    const float* sw3 = sw + 256 * HH;
    const float d = (float)bin * (8.0f / (float)NBINS);
    f32x2 acc = 0.f;
#pragma unroll
    for (int k = 0; k < 16; ++k) {
      float tt = d - (float)k * GS_STEP;
      float ee = __expf(GS_COEFF * tt * tt);
      f32x2 w;
      w.x = fw3[k * HH + j];
      w.y = sw3[k * HH + j];
      acc = __builtin_elementwise_fma((f32x2)(ee), w, acc);
    }
    *(f32x2*)&LUT[bin * 256 + 2 * j] = acc;
  }
}

// ---------------- projection GEMM: C[NN x 512] = H[NN x 128] @ Wp --------
__global__ __launch_bounds__(256) void k_gemm(
    const float* __restrict__ h, const float* __restrict__ Wp,
    const float* __restrict__ biasv,
    float* __restrict__ PD, float* __restrict__ PS) {
  __shared__ float ht[128][68];
  const int tid = threadIdx.x;
  const int n0 = blockIdx.x * 64;
  const int bn0 = blockIdx.y * 128;
  for (int i = tid; i < 64 * 128; i += 256) {
    int ln = i >> 7, k = i & 127;
    int n = n0 + ln;
    ht[k][ln] = (n < NN) ? h[n * HH + k] : 0.f;
  }
  __syncthreads();
  const int tx = tid & 31, ty = tid >> 5;
  const int m0 = ty * 8;
  const float* wp = Wp + bn0 + 4 * tx;
  f32x2 acc[8][2];
#pragma unroll
  for (int mi = 0; mi < 8; ++mi) { acc[mi][0] = 0.f; acc[mi][1] = 0.f; }
  for (int k = 0; k < 128; ++k) {
    const float4 bv = *(const float4*)(wp + k * 512);
    const f32x2 b01 = {bv.x, bv.y}, b23 = {bv.z, bv.w};
    const float4 a0 = *(const float4*)&ht[k][m0];
    const float4 a1 = *(const float4*)&ht[k][m0 + 4];
    const float am[8] = {a0.x, a0.y, a0.z, a0.w, a1.x, a1.y, a1.z, a1.w};
#pragma unroll
    for (int mi = 0; mi < 8; ++mi) {
      acc[mi][0] = __builtin_elementwise_fma((f32x2)(am[mi]), b01, acc[mi][0]);
      acc[mi][1] = __builtin_elementwise_fma((f32x2)(am[mi]), b23, acc[mi][1]);
    }
  }
  const float4 bias4 = *(const float4*)(biasv + bn0 + 4 * tx);
  const f32x2 bb01 = {bias4.x, bias4.y}, bb23 = {bias4.z, bias4.w};
  float* basep = (bn0 < 256) ? PD : PS;
  const int cb = ((bn0 < 256) ? bn0 : bn0 - 256) + 4 * tx;
#pragma unroll
  for (int mi = 0; mi < 8; ++mi) {
    const int n = n0 + m0 + mi;
    if (n < NN) {
      const f32x2 r0 = acc[mi][0] + bb01;
      const f32x2 r1 = acc[mi][1] + bb23;
      float4 st = {r0.x, r0.y, r1.x, r1.y};
      *(float4*)&basep[n * 256 + cb] = st;
    }
  }
}

// ---------------- counting sort of edges by dst ----------------
__global__ __launch_bounds__(256) void k_hist(
    const int* __restrict__ ei, int* __restrict__ deg) {
  int e = blockIdx.x * 256 + threadIdx.x;
  if (e < NE) atomicAdd(&deg[ei[NE + e]], 1);
}

__global__ __launch_bounds__(1024) void k_scan(
    const int* __restrict__ deg, int* __restrict__ cursor,
    int* __restrict__ rowptr) {
  __shared__ int part[1024];
  const int tid = threadIdx.x;
  const int CH = (NN + 1023) / 1024;  // 25
  const int base = tid * CH;
  int s = 0;
  for (int i = 0; i < CH; ++i) {
    int n = base + i;
    if (n < NN) s += deg[n];
  }
  part[tid] = s;
  __syncthreads();
  for (int off = 1; off < 1024; off <<= 1) {
    int t = (tid >= off) ? part[tid - off] : 0;
    __syncthreads();
    part[tid] += t;
    __syncthreads();
  }
  int run = part[tid] - s;
  for (int i = 0; i < CH; ++i) {
    int n = base + i;
    if (n < NN) {
      cursor[n] = run;
      rowptr[n] = run;
      run += deg[n];
    }
  }
  if (tid == 0) rowptr[NN] = NE;
}

__global__ __launch_bounds__(256) void k_scatter(
    const int* __restrict__ ei, const float* __restrict__ eattr,
    int* __restrict__ cursor, int* __restrict__ esrc_s,
    float* __restrict__ attr_s) {
  int e = blockIdx.x * 256 + threadIdx.x;
  if (e >= NE) return;
  const int dst = ei[NE + e];
  const int pos = atomicAdd(&cursor[dst], 1);
  esrc_s[pos] = ei[e];
  attr_s[pos] = eattr[e];
}

// ---------------- node-centric edge kernel: no atomics, PD once per node ----
__global__ __launch_bounds__(256) void k_edge_node(
    const int* __restrict__ rowptr, const int* __restrict__ esrc_s,
    const float* __restrict__ attr_s, const float* __restrict__ LUT,
    const float* __restrict__ PD, const float* __restrict__ PS,
    float* __restrict__ agg) {
  const int tid = threadIdx.x;
  const int g = tid >> 7;       // group 0/1 (128 threads each)
  const int j = tid & 127;      // channel
  const int j2 = 2 * j;
  const int ngroups = gridDim.x * 2;
  for (int n = blockIdx.x * 2 + g; n < NN; n += ngroups) {
    const int rp = rowptr[n];
    const int re = rowptr[n + 1];
    const f32x2 a = *(const f32x2*)&PD[n * 256 + j2];  // once per node
    float macc = 0.f;
    if (rp < re) {
      // depth-2 manual pipeline with named regs (no runtime reg-array idx)
      int src = esrc_s[rp];
      float t = attr_s[rp] * BINSC;
      int bin = min((int)t, NBINS - 1);
      float fr = t - (float)bin;
      f32x2 b = *(const f32x2*)&PS[src * 256 + j2];
      f32x2 v0 = *(const f32x2*)&LUT[bin * 256 + j2];
      f32x2 v1 = *(const f32x2*)&LUT[bin * 256 + 256 + j2];
      for (int e = rp; e < re; ++e) {
        const f32x2 bb = b, w0 = v0, w1 = v1;
        const float frc = fr;
        if (e + 1 < re) {  // prefetch next edge
          const int sn = esrc_s[e + 1];
          const float tn = attr_s[e + 1] * BINSC;
          const int bn = min((int)tn, NBINS - 1);
          fr = tn - (float)bn;
          b = *(const f32x2*)&PS[sn * 256 + j2];
          v0 = *(const f32x2*)&LUT[bn * 256 + j2];
          v1 = *(const f32x2*)&LUT[bn * 256 + 256 + j2];
        }
        f32x2 fs = (a + bb) + w0;
        fs = __builtin_elementwise_fma((f32x2)(frc), w1 - w0, fs);
        const float f = fs.x, s = fs.y;
        const float ef = __builtin_amdgcn_exp2f(-f * LOG2E);
        const float sig = __builtin_amdgcn_rcpf(1.f + ef);
        const float et = __builtin_amdgcn_exp2f(-fabsf(s) * LOG2E);
        const float sp = fmaxf(s, 0.f) + LN2 * __builtin_amdgcn_logf(1.f + et);
        macc = fmaf(sig, sp, macc);
      }
    }
    agg[n * HH + j] = macc;  // plain coalesced store, no atomic, no memset
  }
}

// ---------------- per-channel sum / sumsq ----------------
__global__ __launch_bounds__(256) void k_stats(
    const float* __restrict__ agg, float* __restrict__ stats) {
  const int c = threadIdx.x & 127;
  const int slice = (blockIdx.x * 256 + threadIdx.x) >> 7;
  const int nslices = (gridDim.x * 256) >> 7;
  float s = 0.f, s2 = 0.f;
  for (int n = slice; n < NN; n += nslices) {
    float v = agg[n * HH + c];
    s += v;
    s2 = fmaf(v, v, s2);
  }
  atomicAdd(&stats[c], s);
  atomicAdd(&stats[HH + c], s2);
}

// ---------------- batchnorm + residual + relu ----------------
__global__ __launch_bounds__(256) void k_bn(
    const float* __restrict__ agg, const float* __restrict__ hold,
    const float* __restrict__ stats, const float* __restrict__ g,
    const float* __restrict__ b, float* __restrict__ hnew) {
  int t = blockIdx.x * 256 + threadIdx.x;
  if (t >= NH) return;
  const int c = t & 127;
  const float inv_n = 1.f / (float)NN;
  const float mu = stats[c] * inv_n;
  const float var = stats[HH + c] * inv_n - mu * mu;
  const float rs = rsqrtf(var + 1e-5f);
  const float v = (agg[t] - mu) * rs * g[c] + b[c] + hold[t];
  hnew[t] = fmaxf(v, 0.f);
}

// ---------------- final fc: out = h @ fc_w + fc_b ----------------
__global__ __launch_bounds__(256) void k_fc(
    const float* __restrict__ h, const float* __restrict__ w,
    const float* __restrict__ b, float* __restrict__ out) {
  const int ln = threadIdx.x >> 5;
  const int m = threadIdx.x & 31;
  const int n = blockIdx.x * 8 + ln;
  if (n >= NN || m >= 21) return;
  const float* hr = h + n * HH;
  float acc = b[m];
#pragma unroll 4
  for (int k = 0; k < HH; ++k) acc = fmaf(hr[k], w[k * 21 + m], acc);
  out[n * 21 + m] = acc;
}

extern "C" void kernel_launch(void* const* d_in, const int* in_sizes, int n_in,
                              void* d_out, int out_size, void* d_ws, size_t ws_size,
                              hipStream_t stream) {
  const float* x      = (const float*)d_in[0];
  const float* eattr  = (const float*)d_in[1];
  const float* node_w = (const float*)d_in[2];
  const float* node_b = (const float*)d_in[3];
  const float* f1w    = (const float*)d_in[4];
  const float* f1b    = (const float*)d_in[5];
  const float* s1w    = (const float*)d_in[6];
  const float* s1b    = (const float*)d_in[7];
  const float* bn1g   = (const float*)d_in[8];
  const float* bn1b   = (const float*)d_in[9];
  const float* f2w    = (const float*)d_in[10];
  const float* f2b    = (const float*)d_in[11];
  const float* s2w    = (const float*)d_in[12];
  const float* s2b    = (const float*)d_in[13];
  const float* bn2g   = (const float*)d_in[14];
  const float* bn2b   = (const float*)d_in[15];
  const float* fcw    = (const float*)d_in[16];
  const float* fcb    = (const float*)d_in[17];
  const int*   ei     = (const int*)d_in[18];
  float* out = (float*)d_out;

  float* ws   = (float*)d_ws;
  float* bufA = ws;                          // h0, later agg2/h2
  float* bufB = ws + NH;                     // agg1 -> h1
  float* PD   = ws + 2 * (size_t)NH;         // [NN][256]
  float* PS   = ws + 4 * (size_t)NH;         // [NN][256]
  float* stats = ws + 6 * (size_t)NH;        // 256 floats
  int*   deg    = (int*)(ws + 6 * (size_t)NH + 256);   // NN
  int*   cursor = deg + NN;                  // NN
  int*   rowptr = cursor + NN;               // NN+1
  int*   esrc_s = rowptr + NN + 8;           // NE
  float* attr_s = (float*)(esrc_s + NE);     // NE
  float* Wp1    = attr_s + NE;               // 128*512
  float* bv1    = Wp1 + 128 * 512;           // 512
  float* Wp2    = bv1 + 512;                 // 128*512
  float* bv2    = Wp2 + 128 * 512;           // 512
  float* lut1   = bv2 + 512;                 // (NBINS+1)*256
  float* lut2   = lut1 + (NBINS + 1) * 256;  // (NBINS+1)*256

  const int g_embed = (NH + 255) / 256;
  const int g_bn    = (NH + 255) / 256;
  const int g_e256  = (NE + 255) / 256;
  const dim3 g_gemm((NN + 63) / 64, 4);
  const dim3 g_prep(256 + (NBINS + 2 + 1) / 2, 2);
  const int g_edge  = 6250;   // 12500 groups, ~2 nodes each

  // h0 = x @ node_w + node_b
  k_node_embed<<<g_embed, 256, 0, stream>>>(x, node_w, node_b, bufA);

  // ---- counting sort of edges by dst (reused by both layers) ----
  hipMemsetAsync(deg, 0, NN * 4, stream);
  k_hist<<<g_e256, 256, 0, stream>>>(ei, deg);
  k_scan<<<1, 1024, 0, stream>>>(deg, cursor, rowptr);
  k_scatter<<<g_e256, 256, 0, stream>>>(ei, eattr, cursor, esrc_s, attr_s);

  // ---- prep: pack + LUT for both layers, one dispatch ----
  k_prep<<<g_prep, 256, 0, stream>>>(f1w, s1w, f1b, s1b, f2w, s2w, f2b, s2b,
                                     Wp1, bv1, lut1, Wp2, bv2, lut2);

  // ---- layer 1 ----
  k_gemm<<<g_gemm, 256, 0, stream>>>(bufA, Wp1, bv1, PD, PS);
  hipMemsetAsync(stats, 0, 256 * 4, stream);
  k_edge_node<<<g_edge, 256, 0, stream>>>(rowptr, esrc_s, attr_s, lut1,
                                          PD, PS, bufB);
  k_stats<<<256, 256, 0, stream>>>(bufB, stats);
  k_bn<<<g_bn, 256, 0, stream>>>(bufB, bufA, stats, bn1g, bn1b, bufB);

  // ---- layer 2 ----
  k_gemm<<<g_gemm, 256, 0, stream>>>(bufB, Wp2, bv2, PD, PS);
  hipMemsetAsync(stats, 0, 256 * 4, stream);
  k_edge_node<<<g_edge, 256, 0, stream>>>(rowptr, esrc_s, attr_s, lut2,
                                          PD, PS, bufA);
  k_stats<<<256, 256, 0, stream>>>(bufA, stats);
  k_bn<<<g_bn, 256, 0, stream>>>(bufA, bufB, stats, bn2g, bn2b, bufA);

  // ---- final fc ----
  k_fc<<<(NN + 7) / 8, 256, 0, stream>>>(bufA, fcw, fcb, out);
}

// Round 10
// 449.699 us; speedup vs baseline: 1.2190x; 1.2190x over previous
//
#include <hip/hip_runtime.h>
#include <hip/hip_bf16.h>
#include <math.h>

#define NN 25000
#define NE 400000
#define HH 128
#define NH (NN*HH)
#define EB 64
#define NBINS 256

// gaussian smearing: offset_k = k*8/15, coeff = -0.5/(8/15)^2 = -1.7578125
#define GS_STEP  (8.0f/15.0f)
#define GS_COEFF (-1.7578125f)
#define LOG2E    1.442695041f
#define LN2      0.6931471806f
#define BINSC    ((float)NBINS / 8.0f)

typedef float f32x2 __attribute__((ext_vector_type(2)));

__device__ __forceinline__ f32x2 bf2_unpack(unsigned int u) {
  union { unsigned int i; float f; } lo, hi;
  lo.i = u << 16;            // low ushort = channel 2j   (f)
  hi.i = u & 0xffff0000u;    // high ushort = channel 2j+1 (s)
  f32x2 r; r.x = lo.f; r.y = hi.f;
  return r;
}

// ---------------- node embedding: h = x @ node_w + node_b ----------------
__global__ __launch_bounds__(256) void k_node_embed(
    const float* __restrict__ x, const float* __restrict__ w,
    const float* __restrict__ b, float* __restrict__ h) {
  int t = blockIdx.x * 256 + threadIdx.x;
  if (t >= NH) return;
  int n = t >> 7, j = t & 127;
  const float* xr = x + n * 6;
  float acc = b[j];
#pragma unroll
  for (int k = 0; k < 6; ++k) acc = fmaf(xr[k], w[k * HH + j], acc);
  h[t] = acc;
}

// ---------------- fused prep: weight repack + gaussian LUT, both layers ----
__global__ __launch_bounds__(256) void k_prep(
    const float* __restrict__ f1w, const float* __restrict__ s1w,
    const float* __restrict__ f1b, const float* __restrict__ s1b,
    const float* __restrict__ f2w, const float* __restrict__ s2w,
    const float* __restrict__ f2b, const float* __restrict__ s2b,
    float* __restrict__ Wp1, float* __restrict__ bv1, float* __restrict__ L1,
    float* __restrict__ Wp2, float* __restrict__ bv2, float* __restrict__ L2) {
  const int layer = blockIdx.y;
  const float* fw = layer ? f2w : f1w;
  const float* sw = layer ? s2w : s1w;
  const float* fb = layer ? f2b : f1b;
  const float* sb = layer ? s2b : s1b;
  float* Wp = layer ? Wp2 : Wp1;
  float* biasv = layer ? bv2 : bv1;
  float* LUT = layer ? L2 : L1;
  const int bx = blockIdx.x;
  const int tid = threadIdx.x;
  if (bx < 256) {
    const int t = bx * 256 + tid;
    if (t < 512) biasv[t] = (t < 256) ? ((t & 1) ? sb[t >> 1] : fb[t >> 1]) : 0.f;
    const int k = t >> 9, c = t & 511;
    const int cc = c & 255;
    const int row = ((c >= 256) ? 128 : 0) + k;
    const float* m = (cc & 1) ? sw : fw;
    Wp[t] = m[row * HH + (cc >> 1)];
  } else {
    const int bin = (bx - 256) * 2 + (tid >> 7);
    if (bin > NBINS) return;
    const int j = tid & 127;
    const float* fw3 = fw + 256 * HH;
    const float* sw3 = sw + 256 * HH;
    const float d = (float)bin * (8.0f / (float)NBINS);
    f32x2 acc = 0.f;
#pragma unroll
    for (int k = 0; k < 16; ++k) {
      float tt = d - (float)k * GS_STEP;
      float ee = __expf(GS_COEFF * tt * tt);
      f32x2 w;
      w.x = fw3[k * HH + j];
      w.y = sw3[k * HH + j];
      acc = __builtin_elementwise_fma((f32x2)(ee), w, acc);
    }
    *(f32x2*)&LUT[bin * 256 + 2 * j] = acc;
  }
}

// ---------------- projection GEMM: PD fp32, PS bf16-packed ---------------
__global__ __launch_bounds__(256) void k_gemm(
    const float* __restrict__ h, const float* __restrict__ Wp,
    const float* __restrict__ biasv,
    float* __restrict__ PD, unsigned short* __restrict__ PSh) {
  __shared__ float ht[128][68];
  const int tid = threadIdx.x;
  const int n0 = blockIdx.x * 64;
  const int bn0 = blockIdx.y * 128;
  for (int i = tid; i < 64 * 128; i += 256) {
    int ln = i >> 7, k = i & 127;
    int n = n0 + ln;
    ht[k][ln] = (n < NN) ? h[n * HH + k] : 0.f;
  }
  __syncthreads();
  const int tx = tid & 31, ty = tid >> 5;
  const int m0 = ty * 8;
  const float* wp = Wp + bn0 + 4 * tx;
  f32x2 acc[8][2];
#pragma unroll
  for (int mi = 0; mi < 8; ++mi) { acc[mi][0] = 0.f; acc[mi][1] = 0.f; }
  for (int k = 0; k < 128; ++k) {
    const float4 bv = *(const float4*)(wp + k * 512);
    const f32x2 b01 = {bv.x, bv.y}, b23 = {bv.z, bv.w};
    const float4 a0 = *(const float4*)&ht[k][m0];
    const float4 a1 = *(const float4*)&ht[k][m0 + 4];
    const float am[8] = {a0.x, a0.y, a0.z, a0.w, a1.x, a1.y, a1.z, a1.w};
#pragma unroll
    for (int mi = 0; mi < 8; ++mi) {
      acc[mi][0] = __builtin_elementwise_fma((f32x2)(am[mi]), b01, acc[mi][0]);
      acc[mi][1] = __builtin_elementwise_fma((f32x2)(am[mi]), b23, acc[mi][1]);
    }
  }
  const float4 bias4 = *(const float4*)(biasv + bn0 + 4 * tx);
  const f32x2 bb01 = {bias4.x, bias4.y}, bb23 = {bias4.z, bias4.w};
  const bool isPD = (bn0 < 256);
  const int cb = (isPD ? bn0 : bn0 - 256) + 4 * tx;
#pragma unroll
  for (int mi = 0; mi < 8; ++mi) {
    const int n = n0 + m0 + mi;
    if (n < NN) {
      const f32x2 r0 = acc[mi][0] + bb01;
      const f32x2 r1 = acc[mi][1] + bb23;
      if (isPD) {
        float4 st = {r0.x, r0.y, r1.x, r1.y};
        *(float4*)&PD[n * 256 + cb] = st;
      } else {
        ushort4 st;
        st.x = __hip_bfloat16_raw(__float2bfloat16(r0.x)).x;
        st.y = __hip_bfloat16_raw(__float2bfloat16(r0.y)).x;
        st.z = __hip_bfloat16_raw(__float2bfloat16(r1.x)).x;
        st.w = __hip_bfloat16_raw(__float2bfloat16(r1.y)).x;
        *(ushort4*)&PSh[n * 256 + cb] = st;
      }
    }
  }
}

// ---------------- counting sort of edges by dst ----------------
__global__ __launch_bounds__(256) void k_hist(
    const int* __restrict__ ei, int* __restrict__ deg) {
  int e = blockIdx.x * 256 + threadIdx.x;
  if (e < NE) atomicAdd(&deg[ei[NE + e]], 1);
}

__global__ __launch_bounds__(1024) void k_scan(
    const int* __restrict__ deg, int* __restrict__ cursor) {
  __shared__ int part[1024];
  const int tid = threadIdx.x;
  const int CH = (NN + 1023) / 1024;  // 25
  const int base = tid * CH;
  int s = 0;
  for (int i = 0; i < CH; ++i) {
    int n = base + i;
    if (n < NN) s += deg[n];
  }
  part[tid] = s;
  __syncthreads();
  for (int off = 1; off < 1024; off <<= 1) {
    int t = (tid >= off) ? part[tid - off] : 0;
    __syncthreads();
    part[tid] += t;
    __syncthreads();
  }
  int run = part[tid] - s;
  for (int i = 0; i < CH; ++i) {
    int n = base + i;
    if (n < NN) {
      cursor[n] = run;
      run += deg[n];
    }
  }
}

__global__ __launch_bounds__(256) void k_scatter(
    const int* __restrict__ ei, const float* __restrict__ eattr,
    int* __restrict__ cursor, int* __restrict__ esrc_s,
    int* __restrict__ edst_s, float* __restrict__ attr_s) {
  int e = blockIdx.x * 256 + threadIdx.x;
  if (e >= NE) return;
  const int dst = ei[NE + e];
  const int pos = atomicAdd(&cursor[dst], 1);
  esrc_s[pos] = ei[e];
  edst_s[pos] = dst;
  attr_s[pos] = eattr[e];
}

// ---------------- sorted edge kernel: bf16 PS gathers, 4-deep pipeline ----
__global__ __launch_bounds__(256) void k_edge_sorted(
    const int* __restrict__ esrc_s, const int* __restrict__ edst_s,
    const float* __restrict__ attr_s, const float* __restrict__ LUT,
    const float* __restrict__ PD, const unsigned short* __restrict__ PSh,
    float* __restrict__ agg) {
  __shared__ int ssrc[EB];
  __shared__ int sdst[EB];
  __shared__ int sbin[EB];
  __shared__ float sfrac[EB];
  const int tid = threadIdx.x;
  const int j = tid & 127;
  const int e0 = blockIdx.x * EB;

  if (tid < EB) {
    ssrc[tid] = esrc_s[e0 + tid];
  } else if (tid < 2 * EB) {
    sdst[tid - EB] = edst_s[e0 + tid - EB];
  } else if (tid < 3 * EB) {
    const int le = tid - 2 * EB;
    float t = attr_s[e0 + le] * BINSC;
    int bin = min((int)t, NBINS - 1);
    sbin[le] = bin;
    sfrac[le] = t - (float)bin;
  }
  __syncthreads();

  const int half = tid >> 7;
  const int lbase = half * 32;
  const int j2 = 2 * j;
  float macc = 0.f;
  int cur = -1;
  f32x2 a = 0.f;
  // 4-deep pipeline: packed-bf16 PS word + LUT rows + frac, fully unrolled
  unsigned int b[4];
  f32x2 v0[4], v1[4];
  float fr[4];
#pragma unroll
  for (int p = 0; p < 4; ++p) {
    const int le = lbase + p;
    b[p] = *(const unsigned int*)&PSh[ssrc[le] * 256 + j2];
    const int bn = sbin[le];
    fr[p] = sfrac[le];
    v0[p] = *(const f32x2*)&LUT[bn * 256 + j2];
    v1[p] = *(const f32x2*)&LUT[bn * 256 + 256 + j2];
  }
#pragma unroll
  for (int it = 0; it < 32; ++it) {
    const int sl = it & 3;
    const int le = lbase + it;
    const int dst = sdst[le];
    if (dst != cur) {  // wave-uniform: new dst run
      a = *(const f32x2*)&PD[dst * 256 + j2];
      cur = dst;
    }
    const f32x2 bb = bf2_unpack(b[sl]);
    const f32x2 w0 = v0[sl], w1 = v1[sl];
    const float frc = fr[sl];
    if (it < 28) {  // refill slot with edge it+4
      const int ln = le + 4;
      b[sl] = *(const unsigned int*)&PSh[ssrc[ln] * 256 + j2];
      const int bn = sbin[ln];
      fr[sl] = sfrac[ln];
      v0[sl] = *(const f32x2*)&LUT[bn * 256 + j2];
      v1[sl] = *(const f32x2*)&LUT[bn * 256 + 256 + j2];
    }
    f32x2 fs = (a + bb) + w0;
    fs = __builtin_elementwise_fma((f32x2)(frc), w1 - w0, fs);
    const float f = fs.x, s = fs.y;
    const float ef = __builtin_amdgcn_exp2f(-f * LOG2E);
    const float sig = __builtin_amdgcn_rcpf(1.f + ef);
    const float et = __builtin_amdgcn_exp2f(-fabsf(s) * LOG2E);
    const float sp = fmaxf(s, 0.f) + LN2 * __builtin_amdgcn_logf(1.f + et);
    macc = fmaf(sig, sp, macc);
    const bool fl = (it == 31) || (sdst[le + 1] != dst);
    if (fl) {  // wave-uniform: end of run -> single flush
      atomicAdd(&agg[dst * HH + j], macc);
      macc = 0.f;
    }
  }
}

// ---------------- per-channel sum / sumsq ----------------
__global__ __launch_bounds__(256) void k_stats(
    const float* __restrict__ agg, float* __restrict__ stats) {
  const int c = threadIdx.x & 127;
  const int slice = (blockIdx.x * 256 + threadIdx.x) >> 7;
  const int nslices = (gridDim.x * 256) >> 7;
  float s = 0.f, s2 = 0.f;
  for (int n = slice; n < NN; n += nslices) {
    float v = agg[n * HH + c];
    s += v;
    s2 = fmaf(v, v, s2);
  }
  atomicAdd(&stats[c], s);
  atomicAdd(&stats[HH + c], s2);
}

// ---------------- batchnorm + residual + relu ----------------
__global__ __launch_bounds__(256) void k_bn(
    const float* __restrict__ agg, const float* __restrict__ hold,
    const float* __restrict__ stats, const float* __restrict__ g,
    const float* __restrict__ b, float* __restrict__ hnew) {
  int t = blockIdx.x * 256 + threadIdx.x;
  if (t >= NH) return;
  const int c = t & 127;
  const float inv_n = 1.f / (float)NN;
  const float mu = stats[c] * inv_n;
  const float var = stats[HH + c] * inv_n - mu * mu;
  const float rs = rsqrtf(var + 1e-5f);
  const float v = (agg[t] - mu) * rs * g[c] + b[c] + hold[t];
  hnew[t] = fmaxf(v, 0.f);
}

// ---------------- final fc: out = h @ fc_w + fc_b ----------------
__global__ __launch_bounds__(256) void k_fc(
    const float* __restrict__ h, const float* __restrict__ w,
    const float* __restrict__ b, float* __restrict__ out) {
  const int ln = threadIdx.x >> 5;
  const int m = threadIdx.x & 31;
  const int n = blockIdx.x * 8 + ln;
  if (n >= NN || m >= 21) return;
  const float* hr = h + n * HH;
  float acc = b[m];
#pragma unroll 4
  for (int k = 0; k < HH; ++k) acc = fmaf(hr[k], w[k * 21 + m], acc);
  out[n * 21 + m] = acc;
}

extern "C" void kernel_launch(void* const* d_in, const int* in_sizes, int n_in,
                              void* d_out, int out_size, void* d_ws, size_t ws_size,
                              hipStream_t stream) {
  const float* x      = (const float*)d_in[0];
  const float* eattr  = (const float*)d_in[1];
  const float* node_w = (const float*)d_in[2];
  const float* node_b = (const float*)d_in[3];
  const float* f1w    = (const float*)d_in[4];
  const float* f1b    = (const float*)d_in[5];
  const float* s1w    = (const float*)d_in[6];
  const float* s1b    = (const float*)d_in[7];
  const float* bn1g   = (const float*)d_in[8];
  const float* bn1b   = (const float*)d_in[9];
  const float* f2w    = (const float*)d_in[10];
  const float* f2b    = (const float*)d_in[11];
  const float* s2w    = (const float*)d_in[12];
  const float* s2b    = (const float*)d_in[13];
  const float* bn2g   = (const float*)d_in[14];
  const float* bn2b   = (const float*)d_in[15];
  const float* fcw    = (const float*)d_in[16];
  const float* fcb    = (const float*)d_in[17];
  const int*   ei     = (const int*)d_in[18];
  float* out = (float*)d_out;

  float* ws   = (float*)d_ws;
  float* bufA = ws;                          // h0, later agg2/h2
  float* bufB = ws + NH;                     // agg1 -> h1
  float* PD   = ws + 2 * (size_t)NH;         // [NN][256] fp32
  unsigned short* PSh = (unsigned short*)(ws + 4 * (size_t)NH);  // [NN][256] bf16
  float* stats = ws + 6 * (size_t)NH;        // 256 floats
  int*   deg    = (int*)(ws + 6 * (size_t)NH + 256);   // NN
  int*   cursor = deg + NN;                  // NN
  int*   esrc_s = cursor + NN;               // NE
  int*   edst_s = esrc_s + NE;               // NE
  float* attr_s = (float*)(edst_s + NE);     // NE
  float* Wp1    = attr_s + NE;               // 128*512
  float* bv1    = Wp1 + 128 * 512;           // 512
  float* Wp2    = bv1 + 512;                 // 128*512
  float* bv2    = Wp2 + 128 * 512;           // 512
  float* lut1   = bv2 + 512;                 // (NBINS+1)*256
  float* lut2   = lut1 + (NBINS + 1) * 256;  // (NBINS+1)*256

  const int g_embed = (NH + 255) / 256;
  const int g_edge  = NE / EB;
  const int g_bn    = (NH + 255) / 256;
  const int g_e256  = (NE + 255) / 256;
  const dim3 g_gemm((NN + 63) / 64, 4);
  const dim3 g_prep(256 + (NBINS + 2 + 1) / 2, 2);

  // h0 = x @ node_w + node_b
  k_node_embed<<<g_embed, 256, 0, stream>>>(x, node_w, node_b, bufA);

  // ---- counting sort of edges by dst (reused by both layers) ----
  hipMemsetAsync(deg, 0, NN * 4, stream);
  k_hist<<<g_e256, 256, 0, stream>>>(ei, deg);
  k_scan<<<1, 1024, 0, stream>>>(deg, cursor);
  k_scatter<<<g_e256, 256, 0, stream>>>(ei, eattr, cursor, esrc_s, edst_s, attr_s);

  // ---- prep: pack + LUT for both layers, one dispatch ----
  k_prep<<<g_prep, 256, 0, stream>>>(f1w, s1w, f1b, s1b, f2w, s2w, f2b, s2b,
                                     Wp1, bv1, lut1, Wp2, bv2, lut2);

  // ---- layer 1 ----
  k_gemm<<<g_gemm, 256, 0, stream>>>(bufA, Wp1, bv1, PD, PSh);
  hipMemsetAsync(bufB, 0, (size_t)NH * 4, stream);
  hipMemsetAsync(stats, 0, 256 * 4, stream);
  k_edge_sorted<<<g_edge, 256, 0, stream>>>(esrc_s, edst_s, attr_s, lut1,
                                            PD, PSh, bufB);
  k_stats<<<256, 256, 0, stream>>>(bufB, stats);
  k_bn<<<g_bn, 256, 0, stream>>>(bufB, bufA, stats, bn1g, bn1b, bufB);

  // ---- layer 2 ----
  k_gemm<<<g_gemm, 256, 0, stream>>>(bufB, Wp2, bv2, PD, PSh);
  hipMemsetAsync(bufA, 0, (size_t)NH * 4, stream);
  hipMemsetAsync(stats, 0, 256 * 4, stream);
  k_edge_sorted<<<g_edge, 256, 0, stream>>>(esrc_s, edst_s, attr_s, lut2,
                                            PD, PSh, bufA);
  k_stats<<<256, 256, 0, stream>>>(bufA, stats);
  k_bn<<<g_bn, 256, 0, stream>>>(bufA, bufB, stats, bn2g, bn2b, bufA);

  // ---- final fc ----
  k_fc<<<(NN + 7) / 8, 256, 0, stream>>>(bufA, fcw, fcb, out);
}

// Round 11
// 413.218 us; speedup vs baseline: 1.3266x; 1.0883x over previous
//
#include <hip/hip_runtime.h>
#include <hip/hip_bf16.h>
#include <math.h>

#define NN 25000
#define NE 400000
#define HH 128
#define NH (NN*HH)
#define EB 64
#define NBINS 2048

// gaussian smearing: offset_k = k*8/15, coeff = -0.5/(8/15)^2 = -1.7578125
#define GS_STEP  (8.0f/15.0f)
#define GS_COEFF (-1.7578125f)
#define LOG2E    1.442695041f
#define LN2      0.6931471806f
#define BINSC    ((float)NBINS / 8.0f)

typedef float f32x2 __attribute__((ext_vector_type(2)));

__device__ __forceinline__ f32x2 bf2_unpack(unsigned int u) {
  union { unsigned int i; float f; } lo, hi;
  lo.i = u << 16;            // low ushort = channel 2j   (f)
  hi.i = u & 0xffff0000u;    // high ushort = channel 2j+1 (s)
  f32x2 r; r.x = lo.f; r.y = hi.f;
  return r;
}

__device__ __forceinline__ unsigned int bf2_pack(float f, float s) {
  unsigned int uf = __hip_bfloat16_raw(__float2bfloat16(f)).x;
  unsigned int us = __hip_bfloat16_raw(__float2bfloat16(s)).x;
  return uf | (us << 16);
}

// ---------------- node embedding: h = x @ node_w + node_b ----------------
__global__ __launch_bounds__(256) void k_node_embed(
    const float* __restrict__ x, const float* __restrict__ w,
    const float* __restrict__ b, float* __restrict__ h) {
  int t = blockIdx.x * 256 + threadIdx.x;
  if (t >= NH) return;
  int n = t >> 7, j = t & 127;
  const float* xr = x + n * 6;
  float acc = b[j];
#pragma unroll
  for (int k = 0; k < 6; ++k) acc = fmaf(xr[k], w[k * HH + j], acc);
  h[t] = acc;
}

// ---------------- fused prep: weight repack + bf16 nearest-LUT, both layers
__global__ __launch_bounds__(256) void k_prep(
    const float* __restrict__ f1w, const float* __restrict__ s1w,
    const float* __restrict__ f1b, const float* __restrict__ s1b,
    const float* __restrict__ f2w, const float* __restrict__ s2w,
    const float* __restrict__ f2b, const float* __restrict__ s2b,
    float* __restrict__ Wp1, float* __restrict__ bv1,
    unsigned short* __restrict__ L1,
    float* __restrict__ Wp2, float* __restrict__ bv2,
    unsigned short* __restrict__ L2) {
  const int layer = blockIdx.y;
  const float* fw = layer ? f2w : f1w;
  const float* sw = layer ? s2w : s1w;
  const float* fb = layer ? f2b : f1b;
  const float* sb = layer ? s2b : s1b;
  float* Wp = layer ? Wp2 : Wp1;
  float* biasv = layer ? bv2 : bv1;
  unsigned short* LUT = layer ? L2 : L1;
  const int bx = blockIdx.x;
  const int tid = threadIdx.x;
  if (bx < 256) {
    const int t = bx * 256 + tid;
    if (t < 512) biasv[t] = (t < 256) ? ((t & 1) ? sb[t >> 1] : fb[t >> 1]) : 0.f;
    const int k = t >> 9, c = t & 511;
    const int cc = c & 255;
    const int row = ((c >= 256) ? 128 : 0) + k;
    const float* m = (cc & 1) ? sw : fw;
    Wp[t] = m[row * HH + (cc >> 1)];
  } else {
    const int bin = (bx - 256) * 2 + (tid >> 7);
    if (bin > NBINS) return;
    const int j = tid & 127;
    const float* fw3 = fw + 256 * HH;
    const float* sw3 = sw + 256 * HH;
    const float d = (float)bin * (8.0f / (float)NBINS);
    f32x2 acc = 0.f;
#pragma unroll
    for (int k = 0; k < 16; ++k) {
      float tt = d - (float)k * GS_STEP;
      float ee = __expf(GS_COEFF * tt * tt);
      f32x2 w;
      w.x = fw3[k * HH + j];
      w.y = sw3[k * HH + j];
      acc = __builtin_elementwise_fma((f32x2)(ee), w, acc);
    }
    *(unsigned int*)&LUT[bin * 256 + 2 * j] = bf2_pack(acc.x, acc.y);
  }
}

// ---------------- projection GEMM: PD fp32, PS bf16-packed ---------------
__global__ __launch_bounds__(256) void k_gemm(
    const float* __restrict__ h, const float* __restrict__ Wp,
    const float* __restrict__ biasv,
    float* __restrict__ PD, unsigned short* __restrict__ PSh) {
  __shared__ float ht[128][68];
  const int tid = threadIdx.x;
  const int n0 = blockIdx.x * 64;
  const int bn0 = blockIdx.y * 128;
  for (int i = tid; i < 64 * 128; i += 256) {
    int ln = i >> 7, k = i & 127;
    int n = n0 + ln;
    ht[k][ln] = (n < NN) ? h[n * HH + k] : 0.f;
  }
  __syncthreads();
  const int tx = tid & 31, ty = tid >> 5;
  const int m0 = ty * 8;
  const float* wp = Wp + bn0 + 4 * tx;
  f32x2 acc[8][2];
#pragma unroll
  for (int mi = 0; mi < 8; ++mi) { acc[mi][0] = 0.f; acc[mi][1] = 0.f; }
  for (int k = 0; k < 128; ++k) {
    const float4 bv = *(const float4*)(wp + k * 512);
    const f32x2 b01 = {bv.x, bv.y}, b23 = {bv.z, bv.w};
    const float4 a0 = *(const float4*)&ht[k][m0];
    const float4 a1 = *(const float4*)&ht[k][m0 + 4];
    const float am[8] = {a0.x, a0.y, a0.z, a0.w, a1.x, a1.y, a1.z, a1.w};
#pragma unroll
    for (int mi = 0; mi < 8; ++mi) {
      acc[mi][0] = __builtin_elementwise_fma((f32x2)(am[mi]), b01, acc[mi][0]);
      acc[mi][1] = __builtin_elementwise_fma((f32x2)(am[mi]), b23, acc[mi][1]);
    }
  }
  const float4 bias4 = *(const float4*)(biasv + bn0 + 4 * tx);
  const f32x2 bb01 = {bias4.x, bias4.y}, bb23 = {bias4.z, bias4.w};
  const bool isPD = (bn0 < 256);
  const int cb = (isPD ? bn0 : bn0 - 256) + 4 * tx;
#pragma unroll
  for (int mi = 0; mi < 8; ++mi) {
    const int n = n0 + m0 + mi;
    if (n < NN) {
      const f32x2 r0 = acc[mi][0] + bb01;
      const f32x2 r1 = acc[mi][1] + bb23;
      if (isPD) {
        float4 st = {r0.x, r0.y, r1.x, r1.y};
        *(float4*)&PD[n * 256 + cb] = st;
      } else {
        ushort4 st;
        st.x = __hip_bfloat16_raw(__float2bfloat16(r0.x)).x;
        st.y = __hip_bfloat16_raw(__float2bfloat16(r0.y)).x;
        st.z = __hip_bfloat16_raw(__float2bfloat16(r1.x)).x;
        st.w = __hip_bfloat16_raw(__float2bfloat16(r1.y)).x;
        *(ushort4*)&PSh[n * 256 + cb] = st;
      }
    }
  }
}

// ---------------- counting sort of edges by dst ----------------
__global__ __launch_bounds__(256) void k_hist(
    const int* __restrict__ ei, int* __restrict__ deg) {
  int e = blockIdx.x * 256 + threadIdx.x;
  if (e < NE) atomicAdd(&deg[ei[NE + e]], 1);
}

__global__ __launch_bounds__(1024) void k_scan(
    const int* __restrict__ deg, int* __restrict__ cursor) {
  __shared__ int part[1024];
  const int tid = threadIdx.x;
  const int CH = (NN + 1023) / 1024;  // 25
  const int base = tid * CH;
  int s = 0;
  for (int i = 0; i < CH; ++i) {
    int n = base + i;
    if (n < NN) s += deg[n];
  }
  part[tid] = s;
  __syncthreads();
  for (int off = 1; off < 1024; off <<= 1) {
    int t = (tid >= off) ? part[tid - off] : 0;
    __syncthreads();
    part[tid] += t;
    __syncthreads();
  }
  int run = part[tid] - s;
  for (int i = 0; i < CH; ++i) {
    int n = base + i;
    if (n < NN) {
      cursor[n] = run;
      run += deg[n];
    }
  }
}

__global__ __launch_bounds__(256) void k_scatter(
    const int* __restrict__ ei, const float* __restrict__ eattr,
    int* __restrict__ cursor, int* __restrict__ esrc_s,
    int* __restrict__ edst_s, float* __restrict__ attr_s) {
  int e = blockIdx.x * 256 + threadIdx.x;
  if (e >= NE) return;
  const int dst = ei[NE + e];
  const int pos = atomicAdd(&cursor[dst], 1);
  esrc_s[pos] = ei[e];
  edst_s[pos] = dst;
  attr_s[pos] = eattr[e];
}

// ---------------- sorted edge kernel: bf16 PS + bf16 nearest-LUT ----------
__global__ __launch_bounds__(256) void k_edge_sorted(
    const int* __restrict__ esrc_s, const int* __restrict__ edst_s,
    const float* __restrict__ attr_s, const unsigned short* __restrict__ LUTh,
    const float* __restrict__ PD, const unsigned short* __restrict__ PSh,
    float* __restrict__ agg) {
  __shared__ int ssrc[EB];   // PSh row base (ushort index)
  __shared__ int sdst[EB];
  __shared__ int sbin[EB];   // LUTh row base (ushort index)
  const int tid = threadIdx.x;
  const int j = tid & 127;
  const int e0 = blockIdx.x * EB;

  if (tid < EB) {
    ssrc[tid] = esrc_s[e0 + tid] << 8;
  } else if (tid < 2 * EB) {
    sdst[tid - EB] = edst_s[e0 + tid - EB];
  } else if (tid < 3 * EB) {
    const int le = tid - 2 * EB;
    float t = attr_s[e0 + le] * BINSC;
    sbin[le] = ((int)(t + 0.5f)) << 8;   // nearest bin
  }
  __syncthreads();

  const int half = tid >> 7;
  const int lbase = half * 32;
  const int j2 = 2 * j;
  float macc = 0.f;
  int cur = -1;
  f32x2 a = 0.f;
  // 4-deep pipeline: packed-bf16 PS word + packed-bf16 LUT word, unrolled
  unsigned int b[4], v[4];
#pragma unroll
  for (int p = 0; p < 4; ++p) {
    const int le = lbase + p;
    b[p] = *(const unsigned int*)&PSh[ssrc[le] + j2];
    v[p] = *(const unsigned int*)&LUTh[sbin[le] + j2];
  }
#pragma unroll
  for (int it = 0; it < 32; ++it) {
    const int sl = it & 3;
    const int le = lbase + it;
    const int dst = sdst[le];
    if (dst != cur) {  // wave-uniform: new dst run
      a = *(const f32x2*)&PD[dst * 256 + j2];
      cur = dst;
    }
    const f32x2 bb = bf2_unpack(b[sl]);
    const f32x2 w = bf2_unpack(v[sl]);
    if (it < 28) {  // refill slot with edge it+4
      const int ln = le + 4;
      b[sl] = *(const unsigned int*)&PSh[ssrc[ln] + j2];
      v[sl] = *(const unsigned int*)&LUTh[sbin[ln] + j2];
    }
    const f32x2 fs = (a + bb) + w;
    const float f = fs.x, s = fs.y;
    const float ef = __builtin_amdgcn_exp2f(-f * LOG2E);
    const float sig = __builtin_amdgcn_rcpf(1.f + ef);
    const float et = __builtin_amdgcn_exp2f(-fabsf(s) * LOG2E);
    const float sp = fmaxf(s, 0.f) + LN2 * __builtin_amdgcn_logf(1.f + et);
    macc = fmaf(sig, sp, macc);
    const bool fl = (it == 31) || (sdst[le + 1] != dst);
    if (fl) {  // wave-uniform: end of run -> single flush
      atomicAdd(&agg[dst * HH + j], macc);
      macc = 0.f;
    }
  }
}

// ---------------- per-channel sum / sumsq ----------------
__global__ __launch_bounds__(256) void k_stats(
    const float* __restrict__ agg, float* __restrict__ stats) {
  const int c = threadIdx.x & 127;
  const int slice = (blockIdx.x * 256 + threadIdx.x) >> 7;
  const int nslices = (gridDim.x * 256) >> 7;
  float s = 0.f, s2 = 0.f;
  for (int n = slice; n < NN; n += nslices) {
    float v = agg[n * HH + c];
    s += v;
    s2 = fmaf(v, v, s2);
  }
  atomicAdd(&stats[c], s);
  atomicAdd(&stats[HH + c], s2);
}

// ---------------- batchnorm + residual + relu ----------------
__global__ __launch_bounds__(256) void k_bn(
    const float* __restrict__ agg, const float* __restrict__ hold,
    const float* __restrict__ stats, const float* __restrict__ g,
    const float* __restrict__ b, float* __restrict__ hnew) {
  int t = blockIdx.x * 256 + threadIdx.x;
  if (t >= NH) return;
  const int c = t & 127;
  const float inv_n = 1.f / (float)NN;
  const float mu = stats[c] * inv_n;
  const float var = stats[HH + c] * inv_n - mu * mu;
  const float rs = rsqrtf(var + 1e-5f);
  const float v = (agg[t] - mu) * rs * g[c] + b[c] + hold[t];
  hnew[t] = fmaxf(v, 0.f);
}

// ---------------- final fc: out = h @ fc_w + fc_b ----------------
__global__ __launch_bounds__(256) void k_fc(
    const float* __restrict__ h, const float* __restrict__ w,
    const float* __restrict__ b, float* __restrict__ out) {
  const int ln = threadIdx.x >> 5;
  const int m = threadIdx.x & 31;
  const int n = blockIdx.x * 8 + ln;
  if (n >= NN || m >= 21) return;
  const float* hr = h + n * HH;
  float acc = b[m];
#pragma unroll 4
  for (int k = 0; k < HH; ++k) acc = fmaf(hr[k], w[k * 21 + m], acc);
  out[n * 21 + m] = acc;
}

extern "C" void kernel_launch(void* const* d_in, const int* in_sizes, int n_in,
                              void* d_out, int out_size, void* d_ws, size_t ws_size,
                              hipStream_t stream) {
  const float* x      = (const float*)d_in[0];
  const float* eattr  = (const float*)d_in[1];
  const float* node_w = (const float*)d_in[2];
  const float* node_b = (const float*)d_in[3];
  const float* f1w    = (const float*)d_in[4];
  const float* f1b    = (const float*)d_in[5];
  const float* s1w    = (const float*)d_in[6];
  const float* s1b    = (const float*)d_in[7];
  const float* bn1g   = (const float*)d_in[8];
  const float* bn1b   = (const float*)d_in[9];
  const float* f2w    = (const float*)d_in[10];
  const float* f2b    = (const float*)d_in[11];
  const float* s2w    = (const float*)d_in[12];
  const float* s2b    = (const float*)d_in[13];
  const float* bn2g   = (const float*)d_in[14];
  const float* bn2b   = (const float*)d_in[15];
  const float* fcw    = (const float*)d_in[16];
  const float* fcb    = (const float*)d_in[17];
  const int*   ei     = (const int*)d_in[18];
  float* out = (float*)d_out;

  float* ws   = (float*)d_ws;
  float* bufA = ws;                          // h0, later agg2/h2
  float* bufB = ws + NH;                     // agg1 -> h1
  float* PD   = ws + 2 * (size_t)NH;         // [NN][256] fp32
  unsigned short* PSh = (unsigned short*)(ws + 4 * (size_t)NH);  // [NN][256] bf16
  float* stats = ws + 6 * (size_t)NH;        // 256 floats
  int*   deg    = (int*)(ws + 6 * (size_t)NH + 256);   // NN
  int*   cursor = deg + NN;                  // NN
  int*   esrc_s = cursor + NN;               // NE
  int*   edst_s = esrc_s + NE;               // NE
  float* attr_s = (float*)(edst_s + NE);     // NE
  float* Wp1    = attr_s + NE;               // 128*512
  float* bv1    = Wp1 + 128 * 512;           // 512
  float* Wp2    = bv1 + 512;                 // 128*512
  float* bv2    = Wp2 + 128 * 512;           // 512
  unsigned short* lut1 = (unsigned short*)(bv2 + 512);   // (NBINS+1)*256 bf16
  unsigned short* lut2 = lut1 + (size_t)(NBINS + 1) * 256;

  const int g_embed = (NH + 255) / 256;
  const int g_edge  = NE / EB;
  const int g_bn    = (NH + 255) / 256;
  const int g_e256  = (NE + 255) / 256;
  const dim3 g_gemm((NN + 63) / 64, 4);
  const dim3 g_prep(256 + (NBINS + 2 + 1) / 2, 2);

  // h0 = x @ node_w + node_b
  k_node_embed<<<g_embed, 256, 0, stream>>>(x, node_w, node_b, bufA);

  // ---- counting sort of edges by dst (reused by both layers) ----
  hipMemsetAsync(deg, 0, NN * 4, stream);
  k_hist<<<g_e256, 256, 0, stream>>>(ei, deg);
  k_scan<<<1, 1024, 0, stream>>>(deg, cursor);
  k_scatter<<<g_e256, 256, 0, stream>>>(ei, eattr, cursor, esrc_s, edst_s, attr_s);

  // ---- prep: pack + LUT for both layers, one dispatch ----
  k_prep<<<g_prep, 256, 0, stream>>>(f1w, s1w, f1b, s1b, f2w, s2w, f2b, s2b,
                                     Wp1, bv1, lut1, Wp2, bv2, lut2);

  // ---- layer 1 ----
  k_gemm<<<g_gemm, 256, 0, stream>>>(bufA, Wp1, bv1, PD, PSh);
  hipMemsetAsync(bufB, 0, (size_t)NH * 4, stream);
  hipMemsetAsync(stats, 0, 256 * 4, stream);
  k_edge_sorted<<<g_edge, 256, 0, stream>>>(esrc_s, edst_s, attr_s, lut1,
                                            PD, PSh, bufB);
  k_stats<<<256, 256, 0, stream>>>(bufB, stats);
  k_bn<<<g_bn, 256, 0, stream>>>(bufB, bufA, stats, bn1g, bn1b, bufB);

  // ---- layer 2 ----
  k_gemm<<<g_gemm, 256, 0, stream>>>(bufB, Wp2, bv2, PD, PSh);
  hipMemsetAsync(bufA, 0, (size_t)NH * 4, stream);
  hipMemsetAsync(stats, 0, 256 * 4, stream);
  k_edge_sorted<<<g_edge, 256, 0, stream>>>(esrc_s, edst_s, attr_s, lut2,
                                            PD, PSh, bufA);
  k_stats<<<256, 256, 0, stream>>>(bufA, stats);
  k_bn<<<g_bn, 256, 0, stream>>>(bufA, bufB, stats, bn2g, bn2b, bufA);

  // ---- final fc ----
  k_fc<<<(NN + 7) / 8, 256, 0, stream>>>(bufA, fcw, fcb, out);
}

// Round 12
// 335.543 us; speedup vs baseline: 1.6337x; 1.2315x over previous
//
#include <hip/hip_runtime.h>
#include <hip/hip_bf16.h>
#include <math.h>

#define NN 25000
#define NE 400000
#define HH 128
#define NH (NN*HH)
#define EB 64
#define NBINS 2048

// gaussian smearing: offset_k = k*8/15, coeff = -0.5/(8/15)^2 = -1.7578125
#define GS_STEP  (8.0f/15.0f)
#define GS_COEFF (-1.7578125f)
#define LOG2E    1.442695041f
#define LN2      0.6931471806f
#define BINSC    ((float)NBINS / 8.0f)

typedef float f32x2 __attribute__((ext_vector_type(2)));
typedef float f32x4 __attribute__((ext_vector_type(4)));
typedef short bf16x8 __attribute__((ext_vector_type(8)));

__device__ __forceinline__ f32x2 bf2_unpack(unsigned int u) {
  union { unsigned int i; float f; } lo, hi;
  lo.i = u << 16;
  hi.i = u & 0xffff0000u;
  f32x2 r; r.x = lo.f; r.y = hi.f;
  return r;
}

__device__ __forceinline__ unsigned short bf16_of(float f) {
  return __hip_bfloat16_raw(__float2bfloat16(f)).x;
}

// ---------------- node embedding: h = x @ node_w + node_b ----------------
__global__ __launch_bounds__(256) void k_node_embed(
    const float* __restrict__ x, const float* __restrict__ w,
    const float* __restrict__ b, float* __restrict__ h) {
  int t = blockIdx.x * 256 + threadIdx.x;
  if (t >= NH) return;
  int n = t >> 7, j = t & 127;
  const float* xr = x + n * 6;
  float acc = b[j];
#pragma unroll
  for (int k = 0; k < 6; ++k) acc = fmaf(xr[k], w[k * HH + j], acc);
  h[t] = acc;
}

// ---------------- fused prep: MFMA-fragment weight pack + bf16 LUT ---------
// Wfrag[nt][kt][lane][j] (bf16): B-frag for col-tile nt, k-tile kt.
//   k = 32*kt + 8*(lane>>4) + j ; packed col c = 16*nt + (lane&15)
__global__ __launch_bounds__(256) void k_prep(
    const float* __restrict__ f1w, const float* __restrict__ s1w,
    const float* __restrict__ f1b, const float* __restrict__ s1b,
    const float* __restrict__ f2w, const float* __restrict__ s2w,
    const float* __restrict__ f2b, const float* __restrict__ s2b,
    unsigned short* __restrict__ Wf1, float* __restrict__ bv1,
    unsigned short* __restrict__ L1,
    unsigned short* __restrict__ Wf2, float* __restrict__ bv2,
    unsigned short* __restrict__ L2) {
  const int layer = blockIdx.y;
  const float* fw = layer ? f2w : f1w;
  const float* sw = layer ? s2w : s1w;
  const float* fb = layer ? f2b : f1b;
  const float* sb = layer ? s2b : s1b;
  unsigned short* Wf = layer ? Wf2 : Wf1;
  float* biasv = layer ? bv2 : bv1;
  unsigned short* LUT = layer ? L2 : L1;
  const int bx = blockIdx.x;
  const int tid = threadIdx.x;
  if (bx < 256) {
    const int t = bx * 256 + tid;
    if (t < 512) biasv[t] = (t < 256) ? ((t & 1) ? sb[t >> 1] : fb[t >> 1]) : 0.f;
    const int j = t & 7;
    const int lane = (t >> 3) & 63;
    const int kt = (t >> 9) & 3;
    const int nt = t >> 11;
    const int k = 32 * kt + 8 * (lane >> 4) + j;
    const int c = 16 * nt + (lane & 15);
    const int cc = c & 255;
    const int row = ((c >= 256) ? 128 : 0) + k;
    const float* m = (cc & 1) ? sw : fw;
    Wf[t] = bf16_of(m[row * HH + (cc >> 1)]);
  } else {
    const int bin = (bx - 256) * 2 + (tid >> 7);
    if (bin > NBINS) return;
    const int j = tid & 127;
    const float* fw3 = fw + 256 * HH;
    const float* sw3 = sw + 256 * HH;
    const float d = (float)bin * (8.0f / (float)NBINS);
    f32x2 acc = 0.f;
#pragma unroll
    for (int k = 0; k < 16; ++k) {
      float tt = d - (float)k * GS_STEP;
      float ee = __expf(GS_COEFF * tt * tt);
      f32x2 w;
      w.x = fw3[k * HH + j];
      w.y = sw3[k * HH + j];
      acc = __builtin_elementwise_fma((f32x2)(ee), w, acc);
    }
    *(unsigned int*)&LUT[bin * 256 + 2 * j] =
        (unsigned int)bf16_of(acc.x) | ((unsigned int)bf16_of(acc.y) << 16);
  }
}

// ---------------- MFMA projection GEMM: [128 x 512] tile per 4-wave block --
// A (h rows, bf16) staged fragment-linear in LDS; B from Wfrag (global, L2).
__global__ __launch_bounds__(256) void k_gemm_mfma(
    const float* __restrict__ h, const unsigned short* __restrict__ Wfrag,
    const float* __restrict__ biasv,
    float* __restrict__ PD, unsigned short* __restrict__ PSh) {
  __shared__ unsigned short As[128 * 128];  // 32 KB, fragment-linear
  const int tid = threadIdx.x;
  const int n0 = blockIdx.x * 128;
  const int bn0 = blockIdx.y * 128;       // packed col base (block-uniform)

  // stage A: chunk (n, c) holds h[n0+n][8c..8c+7] -> bf16 at
  // slot16 = ((n>>4)*4 + (c>>2))*64 + (n&15) + 16*(c&3)  (conflict-free)
  {
    const int tn = tid >> 2;
    const int cj = tid & 3;
#pragma unroll
    for (int ii = 0; ii < 2; ++ii) {
      const int n = tn + 64 * ii;
      const int gn = n0 + n;
#pragma unroll
      for (int i = 0; i < 4; ++i) {
        const int c = cj + 4 * i;
        bf16x8 bv;
        if (gn < NN) {
          const float4 p0 = *(const float4*)&h[gn * HH + c * 8];
          const float4 p1 = *(const float4*)&h[gn * HH + c * 8 + 4];
          bv[0] = (short)bf16_of(p0.x); bv[1] = (short)bf16_of(p0.y);
          bv[2] = (short)bf16_of(p0.z); bv[3] = (short)bf16_of(p0.w);
          bv[4] = (short)bf16_of(p1.x); bv[5] = (short)bf16_of(p1.y);
          bv[6] = (short)bf16_of(p1.z); bv[7] = (short)bf16_of(p1.w);
        } else {
          bv = (bf16x8)0;
        }
        const int slot = ((n >> 4) * 4 + (c >> 2)) * 64 + (n & 15) + 16 * (c & 3);
        *(bf16x8*)&As[slot * 8] = bv;
      }
    }
  }
  __syncthreads();

  const int w = tid >> 6;
  const int lane = tid & 63;
  const int mt0 = 2 * w;                  // wave owns row-tiles mt0, mt0+1
  f32x4 acc[2][8];
#pragma unroll
  for (int mi = 0; mi < 2; ++mi)
#pragma unroll
    for (int nt = 0; nt < 8; ++nt) acc[mi][nt] = (f32x4)0.f;

  const int ntg0 = bn0 >> 4;
#pragma unroll
  for (int kt = 0; kt < 4; ++kt) {
    const bf16x8 a0 = *(const bf16x8*)&As[((mt0 * 4 + kt) * 64 + lane) * 8];
    const bf16x8 a1 = *(const bf16x8*)&As[(((mt0 + 1) * 4 + kt) * 64 + lane) * 8];
#pragma unroll
    for (int nt = 0; nt < 8; ++nt) {
      const bf16x8 b =
          *(const bf16x8*)&Wfrag[(((ntg0 + nt) * 4 + kt) * 64 + lane) * 8];
      acc[0][nt] = __builtin_amdgcn_mfma_f32_16x16x32_bf16(a0, b, acc[0][nt], 0, 0, 0);
      acc[1][nt] = __builtin_amdgcn_mfma_f32_16x16x32_bf16(a1, b, acc[1][nt], 0, 0, 0);
    }
  }

  // epilogue: C/D layout col=lane&15, row=(lane>>4)*4+r
  const int colloc = lane & 15;
  const int rbase = (lane >> 4) * 4;
  const bool isPD = (bn0 < 256);
#pragma unroll
  for (int mi = 0; mi < 2; ++mi) {
#pragma unroll
    for (int nt = 0; nt < 8; ++nt) {
      const int c = bn0 + nt * 16 + colloc;
      const float bias = biasv[c];
#pragma unroll
      for (int r = 0; r < 4; ++r) {
        const int n = n0 + (mt0 + mi) * 16 + rbase + r;
        if (n < NN) {
          const float vv = acc[mi][nt][r] + bias;
          if (isPD) PD[n * 256 + c] = vv;
          else PSh[n * 256 + (c - 256)] = bf16_of(vv);
        }
      }
    }
  }
}

// ---------------- counting sort of edges by dst ----------------
__global__ __launch_bounds__(256) void k_hist(
    const int* __restrict__ ei, int* __restrict__ deg) {
  int e = blockIdx.x * 256 + threadIdx.x;
  if (e < NE) atomicAdd(&deg[ei[NE + e]], 1);
}

__global__ __launch_bounds__(1024) void k_scan(
    const int* __restrict__ deg, int* __restrict__ cursor) {
  __shared__ int part[1024];
  const int tid = threadIdx.x;
  const int CH = (NN + 1023) / 1024;  // 25
  const int base = tid * CH;
  int s = 0;
  for (int i = 0; i < CH; ++i) {
    int n = base + i;
    if (n < NN) s += deg[n];
  }
  part[tid] = s;
  __syncthreads();
  for (int off = 1; off < 1024; off <<= 1) {
    int t = (tid >= off) ? part[tid - off] : 0;
    __syncthreads();
    part[tid] += t;
    __syncthreads();
  }
  int run = part[tid] - s;
  for (int i = 0; i < CH; ++i) {
    int n = base + i;
    if (n < NN) {
      cursor[n] = run;
      run += deg[n];
    }
  }
}

__global__ __launch_bounds__(256) void k_scatter(
    const int* __restrict__ ei, const float* __restrict__ eattr,
    int* __restrict__ cursor, int* __restrict__ esrc_s,
    int* __restrict__ edst_s, float* __restrict__ attr_s) {
  int e = blockIdx.x * 256 + threadIdx.x;
  if (e >= NE) return;
  const int dst = ei[NE + e];
  const int pos = atomicAdd(&cursor[dst], 1);
  esrc_s[pos] = ei[e];
  edst_s[pos] = dst;
  attr_s[pos] = eattr[e];
}

// ---------------- sorted edge kernel: bf16 PS + bf16 nearest-LUT ----------
__global__ __launch_bounds__(256) void k_edge_sorted(
    const int* __restrict__ esrc_s, const int* __restrict__ edst_s,
    const float* __restrict__ attr_s, const unsigned short* __restrict__ LUTh,
    const float* __restrict__ PD, const unsigned short* __restrict__ PSh,
    float* __restrict__ agg) {
  __shared__ int ssrc[EB];
  __shared__ int sdst[EB];
  __shared__ int sbin[EB];
  const int tid = threadIdx.x;
  const int j = tid & 127;
  const int e0 = blockIdx.x * EB;

  if (tid < EB) {
    ssrc[tid] = esrc_s[e0 + tid] << 8;
  } else if (tid < 2 * EB) {
    sdst[tid - EB] = edst_s[e0 + tid - EB];
  } else if (tid < 3 * EB) {
    const int le = tid - 2 * EB;
    float t = attr_s[e0 + le] * BINSC;
    sbin[le] = ((int)(t + 0.5f)) << 8;
  }
  __syncthreads();

  const int half = tid >> 7;
  const int lbase = half * 32;
  const int j2 = 2 * j;
  float macc = 0.f;
  int cur = -1;
  f32x2 a = 0.f;
  unsigned int b[4], v[4];
#pragma unroll
  for (int p = 0; p < 4; ++p) {
    const int le = lbase + p;
    b[p] = *(const unsigned int*)&PSh[ssrc[le] + j2];
    v[p] = *(const unsigned int*)&LUTh[sbin[le] + j2];
  }
#pragma unroll
  for (int it = 0; it < 32; ++it) {
    const int sl = it & 3;
    const int le = lbase + it;
    const int dst = sdst[le];
    if (dst != cur) {
      a = *(const f32x2*)&PD[dst * 256 + j2];
      cur = dst;
    }
    const f32x2 bb = bf2_unpack(b[sl]);
    const f32x2 w = bf2_unpack(v[sl]);
    if (it < 28) {
      const int ln = le + 4;
      b[sl] = *(const unsigned int*)&PSh[ssrc[ln] + j2];
      v[sl] = *(const unsigned int*)&LUTh[sbin[ln] + j2];
    }
    const f32x2 fs = (a + bb) + w;
    const float f = fs.x, s = fs.y;
    const float ef = __builtin_amdgcn_exp2f(-f * LOG2E);
    const float sig = __builtin_amdgcn_rcpf(1.f + ef);
    const float et = __builtin_amdgcn_exp2f(-fabsf(s) * LOG2E);
    const float sp = fmaxf(s, 0.f) + LN2 * __builtin_amdgcn_logf(1.f + et);
    macc = fmaf(sig, sp, macc);
    const bool fl = (it == 31) || (sdst[le + 1] != dst);
    if (fl) {
      atomicAdd(&agg[dst * HH + j], macc);
      macc = 0.f;
    }
  }
}

// ---------------- per-channel sum / sumsq ----------------
__global__ __launch_bounds__(256) void k_stats(
    const float* __restrict__ agg, float* __restrict__ stats) {
  const int c = threadIdx.x & 127;
  const int slice = (blockIdx.x * 256 + threadIdx.x) >> 7;
  const int nslices = (gridDim.x * 256) >> 7;
  float s = 0.f, s2 = 0.f;
  for (int n = slice; n < NN; n += nslices) {
    float v = agg[n * HH + c];
    s += v;
    s2 = fmaf(v, v, s2);
  }
  atomicAdd(&stats[c], s);
  atomicAdd(&stats[HH + c], s2);
}

// ---------------- batchnorm + residual + relu ----------------
__global__ __launch_bounds__(256) void k_bn(
    const float* __restrict__ agg, const float* __restrict__ hold,
    const float* __restrict__ stats, const float* __restrict__ g,
    const float* __restrict__ b, float* __restrict__ hnew) {
  int t = blockIdx.x * 256 + threadIdx.x;
  if (t >= NH) return;
  const int c = t & 127;
  const float inv_n = 1.f / (float)NN;
  const float mu = stats[c] * inv_n;
  const float var = stats[HH + c] * inv_n - mu * mu;
  const float rs = rsqrtf(var + 1e-5f);
  const float v = (agg[t] - mu) * rs * g[c] + b[c] + hold[t];
  hnew[t] = fmaxf(v, 0.f);
}

// ---------------- final fc: out = h @ fc_w + fc_b ----------------
__global__ __launch_bounds__(256) void k_fc(
    const float* __restrict__ h, const float* __restrict__ w,
    const float* __restrict__ b, float* __restrict__ out) {
  const int ln = threadIdx.x >> 5;
  const int m = threadIdx.x & 31;
  const int n = blockIdx.x * 8 + ln;
  if (n >= NN || m >= 21) return;
  const float* hr = h + n * HH;
  float acc = b[m];
#pragma unroll 4
  for (int k = 0; k < HH; ++k) acc = fmaf(hr[k], w[k * 21 + m], acc);
  out[n * 21 + m] = acc;
}

extern "C" void kernel_launch(void* const* d_in, const int* in_sizes, int n_in,
                              void* d_out, int out_size, void* d_ws, size_t ws_size,
                              hipStream_t stream) {
  const float* x      = (const float*)d_in[0];
  const float* eattr  = (const float*)d_in[1];
  const float* node_w = (const float*)d_in[2];
  const float* node_b = (const float*)d_in[3];
  const float* f1w    = (const float*)d_in[4];
  const float* f1b    = (const float*)d_in[5];
  const float* s1w    = (const float*)d_in[6];
  const float* s1b    = (const float*)d_in[7];
  const float* bn1g   = (const float*)d_in[8];
  const float* bn1b   = (const float*)d_in[9];
  const float* f2w    = (const float*)d_in[10];
  const float* f2b    = (const float*)d_in[11];
  const float* s2w    = (const float*)d_in[12];
  const float* s2b    = (const float*)d_in[13];
  const float* bn2g   = (const float*)d_in[14];
  const float* bn2b   = (const float*)d_in[15];
  const float* fcw    = (const float*)d_in[16];
  const float* fcb    = (const float*)d_in[17];
  const int*   ei     = (const int*)d_in[18];
  float* out = (float*)d_out;

  float* ws   = (float*)d_ws;
  float* bufA = ws;                          // h0, later agg2/h2
  float* bufB = ws + NH;                     // agg1 -> h1
  float* PD   = ws + 2 * (size_t)NH;         // [NN][256] fp32
  unsigned short* PSh = (unsigned short*)(ws + 4 * (size_t)NH);  // [NN][256] bf16
  float* stats = ws + 6 * (size_t)NH;        // 256 floats
  int*   deg    = (int*)(ws + 6 * (size_t)NH + 256);   // NN
  int*   cursor = deg + NN;                  // NN
  int*   esrc_s = cursor + NN;               // NE
  int*   edst_s = esrc_s + NE;               // NE
  float* attr_s = (float*)(edst_s + NE);     // NE
  unsigned short* Wf1 = (unsigned short*)(attr_s + NE);  // 65536 bf16
  float* bv1    = (float*)(Wf1 + 65536);     // 512
  unsigned short* Wf2 = (unsigned short*)(bv1 + 512);    // 65536 bf16
  float* bv2    = (float*)(Wf2 + 65536);     // 512
  unsigned short* lut1 = (unsigned short*)(bv2 + 512);   // (NBINS+1)*256 bf16
  unsigned short* lut2 = lut1 + (size_t)(NBINS + 1) * 256;

  const int g_embed = (NH + 255) / 256;
  const int g_edge  = NE / EB;
  const int g_bn    = (NH + 255) / 256;
  const int g_e256  = (NE + 255) / 256;
  const dim3 g_gemm((NN + 127) / 128, 4);
  const dim3 g_prep(256 + (NBINS + 2 + 1) / 2, 2);

  // h0 = x @ node_w + node_b
  k_node_embed<<<g_embed, 256, 0, stream>>>(x, node_w, node_b, bufA);

  // ---- counting sort of edges by dst (reused by both layers) ----
  hipMemsetAsync(deg, 0, NN * 4, stream);
  k_hist<<<g_e256, 256, 0, stream>>>(ei, deg);
  k_scan<<<1, 1024, 0, stream>>>(deg, cursor);
  k_scatter<<<g_e256, 256, 0, stream>>>(ei, eattr, cursor, esrc_s, edst_s, attr_s);

  // ---- prep: fragment weight pack + LUT for both layers, one dispatch ----
  k_prep<<<g_prep, 256, 0, stream>>>(f1w, s1w, f1b, s1b, f2w, s2w, f2b, s2b,
                                     Wf1, bv1, lut1, Wf2, bv2, lut2);

  // ---- layer 1 ----
  k_gemm_mfma<<<g_gemm, 256, 0, stream>>>(bufA, Wf1, bv1, PD, PSh);
  hipMemsetAsync(bufB, 0, (size_t)NH * 4, stream);
  hipMemsetAsync(stats, 0, 256 * 4, stream);
  k_edge_sorted<<<g_edge, 256, 0, stream>>>(esrc_s, edst_s, attr_s, lut1,
                                            PD, PSh, bufB);
  k_stats<<<256, 256, 0, stream>>>(bufB, stats);
  k_bn<<<g_bn, 256, 0, stream>>>(bufB, bufA, stats, bn1g, bn1b, bufB);

  // ---- layer 2 ----
  k_gemm_mfma<<<g_gemm, 256, 0, stream>>>(bufB, Wf2, bv2, PD, PSh);
  hipMemsetAsync(bufA, 0, (size_t)NH * 4, stream);
  hipMemsetAsync(stats, 0, 256 * 4, stream);
  k_edge_sorted<<<g_edge, 256, 0, stream>>>(esrc_s, edst_s, attr_s, lut2,
                                            PD, PSh, bufA);
  k_stats<<<256, 256, 0, stream>>>(bufA, stats);
  k_bn<<<g_bn, 256, 0, stream>>>(bufA, bufB, stats, bn2g, bn2b, bufA);

  // ---- final fc ----
  k_fc<<<(NN + 7) / 8, 256, 0, stream>>>(bufA, fcw, fcb, out);
}